// Round 16
// baseline (713.479 us; speedup 1.0000x reference)
//
#include <hip/hip_runtime.h>
#include <math.h>

#define NN 4096
#define DD 512
#define NSL 16
#define SCALE_F 0.044194173824159216f
#define LN_EPS_F 1e-5f
#define ATTN_EPS_F 1e-8f

typedef float4 f4;
typedef __fp16 h2 __attribute__((ext_vector_type(2)));
typedef _Float16 h2f __attribute__((ext_vector_type(2)));
typedef _Float16 h8 __attribute__((ext_vector_type(8)));
typedef float f32x4 __attribute__((ext_vector_type(4)));

__device__ __forceinline__ float dot4f(f4 a, f4 b){
    return a.x*b.x + a.y*b.y + a.z*b.z + a.w*b.w;
}
__device__ __forceinline__ float fdot2u(unsigned a, unsigned b, float c){
    return __builtin_amdgcn_fdot2(__builtin_bit_cast(h2f, a),
                                  __builtin_bit_cast(h2f, b), c, false);
}
__device__ __forceinline__ unsigned pk(float x, float y){
    return __builtin_bit_cast(unsigned, __builtin_amdgcn_cvt_pkrtz(x, y));
}

// ---- prep: slots bcast + row stats + f16 copies of k,v + weight transpose ----
__global__ __launch_bounds__(256) void k_prep(const float* __restrict__ mu,
        const float* __restrict__ kin, const float* __restrict__ vin,
        float* __restrict__ slots, __fp16* __restrict__ slotsh,
        float* __restrict__ kmu, float* __restrict__ krstd,
        float* __restrict__ vmu, float* __restrict__ vrstd,
        __fp16* __restrict__ kh, __fp16* __restrict__ vh,
        const float* __restrict__ Wq, const float* __restrict__ Wih,
        const float* __restrict__ Whh, const float* __restrict__ W1,
        const float* __restrict__ W2,
        uint2* __restrict__ TWq, uint2* __restrict__ TWih, uint2* __restrict__ TWhh,
        uint2* __restrict__ TW1, uint2* __restrict__ TW2){
    int bx = blockIdx.x, t = threadIdx.x;
    int gid = bx*256 + t;
    if (bx < 128){
        int idx = gid;                             // 32768 f4
        f4 v = ((const f4*)mu)[idx & 2047];
        ((f4*)slots)[idx] = v;
        uint2 o; o.x = pk(v.x, v.y); o.y = pk(v.z, v.w);
        ((uint2*)slotsh)[idx] = o;
    }
    int sub = t & 15;
    int rl  = t >> 4;
#pragma unroll
    for (int pass = 0; pass < 8; pass++){
        int task = bx*128 + pass*16 + rl;          // 0..131071
        int half = task >> 16;                     // 0: v, 1: k
        int row  = task & 65535;
        const float* src = half ? kin : vin;
        __fp16* dsth = half ? kh : vh;
        const f4* r4 = (const f4*)(src + (size_t)row*DD);
        uint2* w2 = (uint2*)(dsth + (size_t)row*DD);
        float s = 0.f, ss = 0.f;
#pragma unroll
        for (int k2 = 0; k2 < 8; k2++){
            f4 x = r4[sub + k2*16];
            s  += x.x+x.y+x.z+x.w;
            ss += x.x*x.x+x.y*x.y+x.z*x.z+x.w*x.w;
            uint2 o; o.x = pk(x.x, x.y); o.y = pk(x.z, x.w);
            w2[sub + k2*16] = o;
        }
        for (int o = 1; o < 16; o <<= 1){
            s += __shfl_xor(s, o); ss += __shfl_xor(ss, o);
        }
        if (sub == 0){
            float m = s*(1.f/DD);
            float rs = rsqrtf(ss*(1.f/DD) - m*m + LN_EPS_F);
            if (half){ kmu[row] = m; krstd[row] = rs; }
            else     { vmu[row] = m; vrstd[row] = rs; }
        }
    }
    // weight transpose-pack (f16)
    for (int id = gid; id < 589824; id += 262144){
        const float* W; uint2* TW; int R, local;
        if (id < 65536)      { W = Wq;  TW = TWq;  R = 512;  local = id; }
        else if (id < 262144){ W = Wih; TW = TWih; R = 1536; local = id - 65536; }
        else if (id < 458752){ W = Whh; TW = TWhh; R = 1536; local = id - 262144; }
        else if (id < 524288){ W = W1;  TW = TW1;  R = 512;  local = id - 458752; }
        else                 { W = W2;  TW = TW2;  R = 512;  local = id - 524288; }
        int kk = local / R, c = local - kk*R;
        f4 w = ((const f4*)W)[(size_t)c*128 + kk];
        uint2 o; o.x = pk(w.x, w.y); o.y = pk(w.z, w.w);
        TW[local] = o;
    }
}

// ---- q0: initial q from broadcast slots_mu (16 unique rows), f32 precision ----
__global__ __launch_bounds__(256) void k_q0(const float* __restrict__ mu_,
        const float* __restrict__ Wq, const float* __restrict__ bq,
        const float* __restrict__ gs, const float* __restrict__ bs,
        const float* __restrict__ gk, const float* __restrict__ bk,
        __fp16* __restrict__ qgh, float* __restrict__ C1p, float* __restrict__ C2p){
    __shared__ __align__(16) float rowF[512];
    __shared__ float sm[16];
    int i = blockIdx.x, t = threadIdx.x, lane = t & 63, wv = t >> 6;
    float2 x = ((const float2*)(mu_ + (size_t)i*DD))[t];
    float s = x.x + x.y, ss = x.x*x.x + x.y*x.y;
    for (int o = 32; o; o >>= 1){ s += __shfl_down(s,o); ss += __shfl_down(ss,o); }
    if (lane == 0){ sm[wv] = s; sm[8+wv] = ss; }
    __syncthreads();
    s = sm[0]+sm[1]+sm[2]+sm[3]; ss = sm[8]+sm[9]+sm[10]+sm[11];
    float mu = s*(1.f/DD), rstd = rsqrtf(ss*(1.f/DD) - mu*mu + LN_EPS_F);
    rowF[2*t]   = (x.x-mu)*rstd*gs[2*t]   + bs[2*t];
    rowF[2*t+1] = (x.y-mu)*rstd*gs[2*t+1] + bs[2*t+1];
    __syncthreads();
    float c1p = 0.f, c2p = 0.f;
#pragma unroll
    for (int rep = 0; rep < 2; rep++){
        int c = t + rep*256;
        const f4* wrow = (const f4*)(Wq + (size_t)c*DD);
        const f4* rf = (const f4*)rowF;
        float acc = 0.f;
        for (int k = 0; k < 128; k++) acc += dot4f(rf[k], wrow[k]);
        float q0 = acc + bq[c];
        float qg = q0 * gk[c];
        __fp16 qh = (__fp16)qg;
        for (int b = 0; b < 16; b++)
            qgh[((size_t)(b*16+i))*DD + c] = qh;
        c1p += qg; c2p += q0*bk[c];
    }
    for (int o = 32; o; o >>= 1){ c1p += __shfl_down(c1p,o); c2p += __shfl_down(c2p,o); }
    __syncthreads();
    if (lane == 0){ sm[wv] = c1p; sm[8+wv] = c2p; }
    __syncthreads();
    if (t == 0){
        float r1 = sm[0]+sm[1]+sm[2]+sm[3];
        float r2 = sm[8]+sm[9]+sm[10]+sm[11];
        for (int b = 0; b < 16; b++){
            C1p[b*16+i] = r1; C2p[b*16+i] = r2;
            for (int k = 1; k < 8; k++){
                C1p[k*256 + b*16+i] = 0.f;
                C2p[k*256 + b*16+i] = 0.f;
            }
        }
    }
}

// ---- fused QK^T (MFMA) + inverted softmax + AV partial (paired fdot2) ----
__global__ __launch_bounds__(256, 4) void k_attn_av(const __fp16* __restrict__ kh,
        const __fp16* __restrict__ vh, const __fp16* __restrict__ qgh,
        const float* __restrict__ C1p, const float* __restrict__ C2p,
        const float* __restrict__ kmu, const float* __restrict__ krstd,
        const float* __restrict__ vmu, const float* __restrict__ vrstd,
        float* __restrict__ Sp, float* __restrict__ Mp, __fp16* __restrict__ Uwp,
        float* __restrict__ attn_out, int last){
    __shared__ __align__(16) unsigned qLr[16*260];
    __shared__ __align__(16) unsigned wLp[32*20];
    __shared__ float c1s[NSL], c2s[NSL];
    __shared__ float kmuL[64], krsL[64], vmuL[64], vrsL[64];
    __shared__ float spL[4][NSL], mpL[4][NSL];
    int chunk = blockIdx.x, b = blockIdx.y;
    int t = threadIdx.x, lane = t & 63, wv = t >> 6;

    const unsigned* qsrc = (const unsigned*)(qgh + (size_t)b*NSL*DD);
    for (int e = t; e < 4096; e += 256)
        qLr[(e >> 8)*260 + (e & 255)] = qsrc[e];
    if (t < NSL){
        float c1 = 0.f, c2 = 0.f;
#pragma unroll
        for (int k = 0; k < 8; k++){
            c1 += C1p[k*256 + b*NSL + t];
            c2 += C2p[k*256 + b*NSL + t];
        }
        c1s[t] = c1; c2s[t] = c2;
    }
    {
        int grp = t >> 6, j0 = t & 63;
        size_t gidx = (size_t)b*NN + chunk*64 + j0;
        if (grp == 0) kmuL[j0] = kmu[gidx];
        else if (grp == 1) krsL[j0] = krstd[gidx];
        else if (grp == 2) vmuL[j0] = vmu[gidx];
        else vrsL[j0] = vrstd[gidx];
    }
    __syncthreads();

    int i = lane & 15, g = lane >> 4;
    int jbase = chunk*64 + wv*16;
    const uint4* ka = (const uint4*)(kh + ((size_t)b*NN + jbase + i)*DD);
    const uint4* qb4 = (const uint4*)qLr;
    f32x4 acc = {0.f, 0.f, 0.f, 0.f};
#pragma unroll
    for (int ks = 0; ks < 16; ks++){
        uint4 af = ka[ks*4 + g];
        uint4 bf = qb4[i*65 + ks*4 + g];
        acc = __builtin_amdgcn_mfma_f32_16x16x32_f16(
                  __builtin_bit_cast(h8, af), __builtin_bit_cast(h8, bf), acc, 0, 0, 0);
    }
    float c1i = c1s[i], c2i = c2s[i];
    float a4[4], w4v[4];
    float S_part = 0.f, M_part = 0.f;
#pragma unroll
    for (int r = 0; r < 4; r++){
        int jl = g*4 + r;
        float mu = kmuL[wv*16 + jl], rstd = krsL[wv*16 + jl];
        float dv = SCALE_F*(rstd*(acc[r] - mu*c1i) + c2i);
        float mx = dv;
        mx = fmaxf(mx, __shfl_xor(mx, 1));
        mx = fmaxf(mx, __shfl_xor(mx, 2));
        mx = fmaxf(mx, __shfl_xor(mx, 4));
        mx = fmaxf(mx, __shfl_xor(mx, 8));
        float e = __expf(dv - mx);
        float se = e;
        se += __shfl_xor(se, 1);
        se += __shfl_xor(se, 2);
        se += __shfl_xor(se, 4);
        se += __shfl_xor(se, 8);
        float a = e/se + ATTN_EPS_F;
        a4[r] = a;
        float rv = vrsL[wv*16 + jl], vm = vmuL[wv*16 + jl];
        w4v[r] = a*rv;
        S_part += a;
        M_part += a*rv*vm;
    }
    wLp[(wv*8 + g*2)*20 + i]     = pk(w4v[0], w4v[1]);
    wLp[(wv*8 + g*2 + 1)*20 + i] = pk(w4v[2], w4v[3]);
    S_part += __shfl_xor(S_part, 16);
    S_part += __shfl_xor(S_part, 32);
    M_part += __shfl_xor(M_part, 16);
    M_part += __shfl_xor(M_part, 32);
    if (lane < 16){ spL[wv][lane] = S_part; mpL[wv][lane] = M_part; }
    if (last){
#pragma unroll
        for (int r = 0; r < 4; r++)
            attn_out[((size_t)b*NSL + i)*NN + jbase + g*4 + r] = a4[r];
    }
    __syncthreads();

    if (t < NSL)
        Sp[((size_t)b*NSL + t)*64 + chunk] = spL[0][t]+spL[1][t]+spL[2][t]+spL[3][t];
    else if (t < 2*NSL){
        int ii = t - NSL;
        Mp[((size_t)b*NSL + ii)*64 + chunk] = mpL[0][ii]+mpL[1][ii]+mpL[2][ii]+mpL[3][ii];
    }

    f4 ax[4], ay[4];
#pragma unroll
    for (int g2 = 0; g2 < 4; g2++){ ax[g2] = f4{0,0,0,0}; ay[g2] = f4{0,0,0,0}; }
    const unsigned* v2h = (const unsigned*)(vh + ((size_t)b*NN + (size_t)chunk*64)*DD);
#pragma unroll 2
    for (int p = 0; p < 32; p++){
        unsigned vu0 = v2h[(size_t)(2*p)*256 + t];
        unsigned vu1 = v2h[(size_t)(2*p+1)*256 + t];
        unsigned pd0 = __builtin_amdgcn_perm(vu1, vu0, 0x05040100u);
        unsigned pd1 = __builtin_amdgcn_perm(vu1, vu0, 0x07060302u);
        const uint4* wp4 = (const uint4*)(wLp + p*20);
#pragma unroll
        for (int g2 = 0; g2 < 4; g2++){
            uint4 w = wp4[g2];
            ax[g2].x = fdot2u(w.x, pd0, ax[g2].x);
            ax[g2].y = fdot2u(w.y, pd0, ax[g2].y);
            ax[g2].z = fdot2u(w.z, pd0, ax[g2].z);
            ax[g2].w = fdot2u(w.w, pd0, ax[g2].w);
            ay[g2].x = fdot2u(w.x, pd1, ay[g2].x);
            ay[g2].y = fdot2u(w.y, pd1, ay[g2].y);
            ay[g2].z = fdot2u(w.z, pd1, ay[g2].z);
            ay[g2].w = fdot2u(w.w, pd1, ay[g2].w);
        }
    }
#pragma unroll
    for (int g2 = 0; g2 < 4; g2++){
        const float* px = (const float*)&ax[g2];
        const float* py = (const float*)&ay[g2];
#pragma unroll
        for (int c4 = 0; c4 < 4; c4++){
            int ii = g2*4 + c4;
            ((unsigned*)Uwp)[(((size_t)(b*NSL + ii))*64 + chunk)*256 + t] = pk(px[c4], py[c4]);
        }
    }
}

// ---- updates = gv*(sum Uwp - M)/S + bv -> updh (f16) ----
__global__ __launch_bounds__(256) void k_upd(const __fp16* __restrict__ Uwp,
        const float* __restrict__ Sp, const float* __restrict__ Mp,
        const float* __restrict__ gv, const float* __restrict__ bv,
        __fp16* __restrict__ updh){
    __shared__ float sm[2];
    int m = blockIdx.x, t = threadIdx.x;
    if (t < 128){
        float val = (t < 64) ? Sp[(size_t)m*64 + (t&63)] : Mp[(size_t)m*64 + (t&63)];
        for (int o = 1; o < 64; o <<= 1) val += __shfl_xor(val, o);
        if (t == 0)  sm[0] = val;
        if (t == 64) sm[1] = val;
    }
    __syncthreads();
    float Sv = sm[0], Mv = sm[1];
    float rS = 1.f/Sv;
    float accx = 0.f, accy = 0.f;
    const unsigned* base = (const unsigned*)Uwp + (size_t)m*64*256 + t;
#pragma unroll 8
    for (int ch = 0; ch < 64; ch++){
        h2 u = __builtin_bit_cast(h2, base[(size_t)ch*256]);
        accx += (float)u.x; accy += (float)u.y;
    }
    float2 gvv = ((const float2*)gv)[t];
    float2 bvv = ((const float2*)bv)[t];
    float ox = gvv.x*(accx - Mv)*rS + bvv.x;
    float oy = gvv.y*(accy - Mv)*rS + bvv.y;
    ((unsigned*)updh)[(size_t)m*256 + t] = pk(ox, oy);
}

// ---- GRU gate matmuls, f16 + split-K x2: grid (32 cc, 16 mg, 2 ks) ----
__global__ __launch_bounds__(256) void k_gru_mm(const __fp16* __restrict__ xh, const __fp16* __restrict__ hh,
        const uint2* __restrict__ TWih, const float* __restrict__ bih,
        const uint2* __restrict__ TWhh, const float* __restrict__ bhh,
        float* __restrict__ gpA, float* __restrict__ gpB){
    int lane = threadIdx.x & 63, wv = threadIdx.x >> 6;
    int c = blockIdx.x*64 + lane;
    int m0 = blockIdx.y*16 + wv*4;
    int ks = blockIdx.z;
    int k0 = ks*64, k1 = k0 + 64;
    float* gp = ks ? gpB : gpA;
    int type = c >> 9;
    const uint2* x2 = (const uint2*)xh;
    const uint2* h2_ = (const uint2*)hh;
    float acc[4] = {0,0,0,0};
    float bias;
    if (type <= 1){
#pragma unroll 2
        for (int kk = k0; kk < k1; kk++){
            uint2 wa = TWih[(size_t)kk*1536 + c];
            uint2 wb = TWhh[(size_t)kk*1536 + c];
#pragma unroll
            for (int mm = 0; mm < 4; mm++){
                uint2 xa = x2[(size_t)(m0+mm)*128 + kk];
                uint2 ha = h2_[(size_t)(m0+mm)*128 + kk];
                acc[mm] = fdot2u(wa.x, xa.x, acc[mm]);
                acc[mm] = fdot2u(wa.y, xa.y, acc[mm]);
                acc[mm] = fdot2u(wb.x, ha.x, acc[mm]);
                acc[mm] = fdot2u(wb.y, ha.y, acc[mm]);
            }
        }
        bias = bih[c] + bhh[c];
    } else if (type == 2){
#pragma unroll 2
        for (int kk = k0; kk < k1; kk++){
            uint2 wa = TWih[(size_t)kk*1536 + c];
#pragma unroll
            for (int mm = 0; mm < 4; mm++){
                uint2 xa = x2[(size_t)(m0+mm)*128 + kk];
                acc[mm] = fdot2u(wa.x, xa.x, acc[mm]);
                acc[mm] = fdot2u(wa.y, xa.y, acc[mm]);
            }
        }
        bias = bih[c];
    } else {
        int cr = c - 512;
#pragma unroll 2
        for (int kk = k0; kk < k1; kk++){
            uint2 wb = TWhh[(size_t)kk*1536 + cr];
#pragma unroll
            for (int mm = 0; mm < 4; mm++){
                uint2 ha = h2_[(size_t)(m0+mm)*128 + kk];
                acc[mm] = fdot2u(wb.x, ha.x, acc[mm]);
                acc[mm] = fdot2u(wb.y, ha.y, acc[mm]);
            }
        }
        bias = bhh[cr];
    }
    float bout = ks ? 0.f : bias;
#pragma unroll
    for (int mm = 0; mm < 4; mm++)
        gp[(size_t)(m0+mm)*2048 + c] = acc[mm] + bout;
}

// ---- tail1: GRU-elem + LN(gff,bff) + FFN1 -> hidh; cc==0 writes slots2 ----
__global__ __launch_bounds__(256) void k_tail1(const float* __restrict__ gpA,
        const float* __restrict__ gpB, const float* __restrict__ slots,
        const float* __restrict__ gff, const float* __restrict__ bff,
        const uint2* __restrict__ TW1, const float* __restrict__ b1,
        float* __restrict__ slots2, __fp16* __restrict__ hidh){
    __shared__ uint2 rowh[4][128];
    int lane = threadIdx.x & 63, wv = threadIdx.x >> 6;
    int m = blockIdx.y*4 + wv;
    int c = blockIdx.x*64 + lane;
    const f4* g0 = (const f4*)(gpA + (size_t)m*2048);
    const f4* g1 = (const f4*)(gpB + (size_t)m*2048);
    const f4* h4 = (const f4*)(slots + (size_t)m*DD);
    f4 s2v[2];
    float s = 0.f, ss = 0.f;
#pragma unroll
    for (int half = 0; half < 2; half++){
        int e = lane*2 + half;
        f4 rp = g0[e],      zp = g0[128+e],  nx = g0[256+e],  nh = g0[384+e];
        f4 rq = g1[e],      zq = g1[128+e],  ny = g1[256+e],  nz = g1[384+e];
        rp.x+=rq.x; rp.y+=rq.y; rp.z+=rq.z; rp.w+=rq.w;
        zp.x+=zq.x; zp.y+=zq.y; zp.z+=zq.z; zp.w+=zq.w;
        nx.x+=ny.x; nx.y+=ny.y; nx.z+=ny.z; nx.w+=ny.w;
        nh.x+=nz.x; nh.y+=nz.y; nh.z+=nz.z; nh.w+=nz.w;
        f4 hv = h4[e];
        f4 o;
        {
            float r = 1.f/(1.f + __expf(-rp.x));
            float z = 1.f/(1.f + __expf(-zp.x));
            float n = tanhf(nx.x + r*nh.x);
            o.x = (1.f - z)*n + z*hv.x;
            r = 1.f/(1.f + __expf(-rp.y)); z = 1.f/(1.f + __expf(-zp.y));
            n = tanhf(nx.y + r*nh.y);
            o.y = (1.f - z)*n + z*hv.y;
            r = 1.f/(1.f + __expf(-rp.z)); z = 1.f/(1.f + __expf(-zp.z));
            n = tanhf(nx.z + r*nh.z);
            o.z = (1.f - z)*n + z*hv.z;
            r = 1.f/(1.f + __expf(-rp.w)); z = 1.f/(1.f + __expf(-zp.w));
            n = tanhf(nx.w + r*nh.w);
            o.w = (1.f - z)*n + z*hv.w;
        }
        s2v[half] = o;
        s  += o.x+o.y+o.z+o.w;
        ss += o.x*o.x+o.y*o.y+o.z*o.z+o.w*o.w;
        if (blockIdx.x == 0)
            ((f4*)(slots2 + (size_t)m*DD))[e] = o;
    }
    for (int o = 32; o; o >>= 1){ s += __shfl_down(s,o); ss += __shfl_down(ss,o); }
    s = __shfl(s,0); ss = __shfl(ss,0);
    float mu = s*(1.f/DD);
    float rstd = rsqrtf(ss*(1.f/DD) - mu*mu + LN_EPS_F);
    const f4* gg4 = (const f4*)gff; const f4* bb4 = (const f4*)bff;
#pragma unroll
    for (int half = 0; half < 2; half++){
        int e = lane*2 + half;
        f4 gg = gg4[e], bb = bb4[e], o = s2v[half], n;
        n.x = (o.x-mu)*rstd*gg.x + bb.x;
        n.y = (o.y-mu)*rstd*gg.y + bb.y;
        n.z = (o.z-mu)*rstd*gg.z + bb.z;
        n.w = (o.w-mu)*rstd*gg.w + bb.w;
        rowh[wv][e] = uint2{pk(n.x,n.y), pk(n.z,n.w)};
    }
    __syncthreads();
    float acc = 0.f;
    for (int kk = 0; kk < 128; kk++){
        uint2 q2 = rowh[wv][kk];
        uint2 w2 = TW1[(size_t)kk*512 + c];
        acc = fdot2u(w2.x, q2.x, acc);
        acc = fdot2u(w2.y, q2.y, acc);
    }
    float hv = fmaxf(acc + b1[c], 0.f);
    hidh[(size_t)m*DD + c] = (__fp16)hv;
}

// ---- ffn2q: FFN2 (full row, redundant) + LN(gs,bs) + q-proj slice ----
// grid (8 cc, 64 mg), 256 thr; wave = row m = mg*4+wv.
__global__ __launch_bounds__(256) void k_ffn2q(const __fp16* __restrict__ hidh,
        const uint2* __restrict__ TW2, const float* __restrict__ b2,
        const float* __restrict__ slots2,
        const float* __restrict__ gs, const float* __restrict__ bs,
        const uint2* __restrict__ TWq, const float* __restrict__ bq,
        const float* __restrict__ gk, const float* __restrict__ bk,
        float* __restrict__ slots, __fp16* __restrict__ slotsh,
        __fp16* __restrict__ qgh, float* __restrict__ C1p, float* __restrict__ C2p,
        float* __restrict__ out_slots, int last){
    __shared__ __align__(16) uint4 hidL[4][64];      // 4 KB
    __shared__ __align__(16) unsigned rowq[4][256];  // 4 KB
    int lane = threadIdx.x & 63, wv = threadIdx.x >> 6;
    int cc = blockIdx.x;
    int m = blockIdx.y*4 + wv;
    hidL[wv][lane] = ((const uint4*)(hidh + (size_t)m*DD))[lane];
    __syncthreads();
    const uint4* tw2v = (const uint4*)TW2;
    const uint2* hrow = (const uint2*)&hidL[wv][0];
    float2 v0[4];
    float s = 0.f, ss = 0.f;
#pragma unroll
    for (int j = 0; j < 4; j++){
        int p = lane + j*64;                 // dword-pair index: cols 2p, 2p+1
        float a0 = 0.f, a1 = 0.f;
#pragma unroll 4
        for (int kk = 0; kk < 128; kk++){
            uint4 w = tw2v[(size_t)kk*256 + p];
            uint2 hq = hrow[kk];
            a0 = fdot2u(w.x, hq.x, a0);
            a0 = fdot2u(w.y, hq.y, a0);
            a1 = fdot2u(w.z, hq.x, a1);
            a1 = fdot2u(w.w, hq.y, a1);
        }
        float2 sl2 = ((const float2*)(slots2 + (size_t)m*DD))[p];
        float2 bb = ((const float2*)b2)[p];
        float2 v; v.x = sl2.x + a0 + bb.x; v.y = sl2.y + a1 + bb.y;
        v0[j] = v;
        s += v.x + v.y; ss += v.x*v.x + v.y*v.y;
    }
    for (int o = 32; o; o >>= 1){ s += __shfl_down(s,o); ss += __shfl_down(ss,o); }
    s = __shfl(s,0); ss = __shfl(ss,0);
    float mu = s*(1.f/DD), rstd = rsqrtf(ss*(1.f/DD) - mu*mu + LN_EPS_F);
    int jown = cc >> 1, half = cc & 1;
#pragma unroll
    for (int j = 0; j < 4; j++){
        int p = lane + j*64;
        float2 v = v0[j];
        if (j == jown && (lane >> 5) == half){
            ((float2*)(slots + (size_t)m*DD))[p] = v;
            ((unsigned*)slotsh)[(size_t)m*256 + p] = pk(v.x, v.y);
            if (last) ((float2*)(out_slots + (size_t)m*DD))[p] = v;
        }
        if (!last){
            float2 gg = ((const float2*)gs)[p];
            float2 bb = ((const float2*)bs)[p];
            float nx_ = (v.x-mu)*rstd*gg.x + bb.x;
            float ny_ = (v.y-mu)*rstd*gg.y + bb.y;
            rowq[wv][p] = pk(nx_, ny_);
        }
    }
    if (last) return;
    __syncthreads();
    int c = cc*64 + lane;
    const uint2* rq = (const uint2*)&rowq[wv][0];
    float acc = 0.f;
#pragma unroll 4
    for (int kk = 0; kk < 128; kk++){
        uint2 w = TWq[(size_t)kk*512 + c];
        uint2 q = rq[kk];
        acc = fdot2u(w.x, q.x, acc);
        acc = fdot2u(w.y, q.y, acc);
    }
    float q0 = acc + bq[c];
    float qg = q0 * gk[c];
    qgh[(size_t)m*DD + c] = (__fp16)qg;
    float r1 = qg, r2 = q0*bk[c];
    for (int o = 32; o; o >>= 1){ r1 += __shfl_down(r1,o); r2 += __shfl_down(r2,o); }
    if (lane == 0){ C1p[cc*256 + m] = r1; C2p[cc*256 + m] = r2; }
}

// ---- features ----
__global__ __launch_bounds__(256) void k_features(const float* __restrict__ prompts, const float* __restrict__ slots,
        const float* __restrict__ attn, float* __restrict__ pf, float* __restrict__ sf, float* __restrict__ sf2){
    int b = blockIdx.y;
    int pbase = blockIdx.x*32;
    int t = threadIdx.x;
    __shared__ float al[NSL][33];
    for (int idx = t; idx < NSL*32; idx += 256){
        int i = idx >> 5, pp = idx & 31;
        al[i][pp] = attn[((size_t)b*NSL + i)*NN + pbase + pp];
    }
    float2 pr[NSL], sl[NSL];
    const float2* p2 = (const float2*)prompts;
    const float2* s2 = (const float2*)(slots + (size_t)b*NSL*DD);
#pragma unroll
    for (int i = 0; i < NSL; i++){ pr[i] = p2[i*256+t]; sl[i] = s2[i*256+t]; }
    __syncthreads();
    for (int pp = 0; pp < 32; pp++){
        float a0=0.f, a1=0.f, c0=0.f, c1=0.f;
#pragma unroll
        for (int i = 0; i < NSL; i++){
            float a = al[i][pp];
            a0 += a*pr[i].x; a1 += a*pr[i].y;
            c0 += a*sl[i].x; c1 += a*sl[i].y;
        }
        size_t o = ((size_t)b*NN + pbase + pp)*DD + 2*t;
        float2 pv; pv.x=a0; pv.y=a1;
        float2 sv; sv.x=c0; sv.y=c1;
        *(float2*)(pf + o)  = pv;
        *(float2*)(sf + o)  = sv;
        *(float2*)(sf2 + o) = sv;
    }
}

extern "C" void kernel_launch(void* const* d_in, const int* in_sizes, int n_in,
                              void* d_out, int out_size, void* d_ws, size_t ws_size,
                              hipStream_t stream) {
    const float* k_inp   = (const float*)d_in[2];
    const float* v_inp   = (const float*)d_in[3];
    const float* slots_mu= (const float*)d_in[4];
    const float* prompts = (const float*)d_in[5];
    const float* Wq      = (const float*)d_in[6];
    const float* bq      = (const float*)d_in[7];
    const float* W_ih    = (const float*)d_in[8];
    const float* b_ih    = (const float*)d_in[9];
    const float* W_hh    = (const float*)d_in[10];
    const float* b_hh    = (const float*)d_in[11];
    const float* W1      = (const float*)d_in[12];
    const float* b1      = (const float*)d_in[13];
    const float* W2      = (const float*)d_in[14];
    const float* b2      = (const float*)d_in[15];
    const float* gk      = (const float*)d_in[16];
    const float* bk      = (const float*)d_in[17];
    const float* gv      = (const float*)d_in[18];
    const float* bv      = (const float*)d_in[19];
    const float* gs      = (const float*)d_in[20];
    const float* bs      = (const float*)d_in[21];
    const float* gff     = (const float*)d_in[22];
    const float* bff     = (const float*)d_in[23];

    float* ws = (float*)d_ws;
    float* slots   = ws + 0;           // 131072
    float* slots2  = ws + 131072;      // 131072
    float* gp      = ws + 262144;      // 524288 -> 786432
    float* C1p     = ws + 786432;      // 2048
    float* C2p     = ws + 788480;      // 2048
    float* kmu     = ws + 790528;      // 65536
    float* krstd   = ws + 856064;      // 65536
    float* vmu     = ws + 921600;      // 65536
    float* vrstd   = ws + 987136;      // 65536
    float* Sp      = ws + 1052672;     // 16384
    float* Mp      = ws + 1069056;     // 16384 -> 1085440
    __fp16* slotsh = (__fp16*)(ws + 1085440);   // 65536 float-slots
    __fp16* updh   = (__fp16*)(ws + 1150976);   // 65536
    __fp16* hidh   = (__fp16*)(ws + 1216512);   // 65536
    __fp16* qgh    = (__fp16*)(ws + 1282048);   // 65536 -> 1347584
    uint2* TWqh  = (uint2*)(ws + 1347584);      // 131072 -> 1478656
    uint2* TWihh = (uint2*)(ws + 1478656);      // 393216 -> 1871872
    uint2* TWhhh = (uint2*)(ws + 1871872);      // 393216 -> 2265088
    uint2* TW1h  = (uint2*)(ws + 2265088);      // 131072 -> 2396160
    uint2* TW2h  = (uint2*)(ws + 2396160);      // 131072 -> 2527232 floats = 10.1 MB

    float* out      = (float*)d_out;
    float* attn_out = out + 131072;
    float* pf       = out + 1179648;
    float* sf       = pf + 33554432;
    float* sf2      = sf + 33554432;
    __fp16* Uwp     = (__fp16*)pf;           // 8.4M f16 scratch in pf region
    float* gpB      = pf + 16777216;         // 0.5M floats scratch in pf region
    __fp16* kh      = (__fp16*)sf;           // 67 MB f16 k in sf region
    __fp16* vh      = (__fp16*)sf2;          // 67 MB f16 v in sf2 region
    // pf/sf/sf2 scratch fully consumed before k_features overwrites those regions

    k_prep<<<1024, 256, 0, stream>>>(slots_mu, k_inp, v_inp, slots, slotsh,
                                     kmu, krstd, vmu, vrstd, kh, vh,
                                     Wq, W_ih, W_hh, W1, W2,
                                     TWqh, TWihh, TWhhh, TW1h, TW2h);
    k_q0<<<16, 256, 0, stream>>>(slots_mu, Wq, bq, gs, bs, gk, bk, qgh, C1p, C2p);

    for (int it = 0; it < 3; it++){
        int last = (it == 2);
        k_attn_av<<<dim3(64,16), 256, 0, stream>>>(kh, vh, qgh, C1p, C2p,
                                                   kmu, krstd, vmu, vrstd,
                                                   Sp, Mp, Uwp, attn_out, last);
        k_upd<<<256, 256, 0, stream>>>(Uwp, Sp, Mp, gv, bv, updh);
        k_gru_mm<<<dim3(32,16,2), 256, 0, stream>>>(updh, slotsh, TWihh, b_ih, TWhhh, b_hh, gp, gpB);
        k_tail1<<<dim3(8,64), 256, 0, stream>>>(gp, gpB, slots, gff, bff, TW1h, b1, slots2, hidh);
        k_ffn2q<<<dim3(8,64), 256, 0, stream>>>(hidh, TW2h, b2, slots2, gs, bs,
                                                TWqh, bq, gk, bk,
                                                slots, slotsh, qgh, C1p, C2p, out, last);
    }

    k_features<<<dim3(128,16), 256, 0, stream>>>(prompts, slots, attn_out, pf, sf, sf2);
}

// Round 17
// 558.315 us; speedup vs baseline: 1.2779x; 1.2779x over previous
//
#include <hip/hip_runtime.h>
#include <math.h>

#define NN 4096
#define DD 512
#define NSL 16
#define SCALE_F 0.044194173824159216f
#define LN_EPS_F 1e-5f
#define ATTN_EPS_F 1e-8f

typedef float4 f4;
typedef __fp16 h2 __attribute__((ext_vector_type(2)));
typedef _Float16 h2f __attribute__((ext_vector_type(2)));
typedef _Float16 h8 __attribute__((ext_vector_type(8)));
typedef float f32x4 __attribute__((ext_vector_type(4)));

__device__ __forceinline__ float dot4f(f4 a, f4 b){
    return a.x*b.x + a.y*b.y + a.z*b.z + a.w*b.w;
}
__device__ __forceinline__ float fdot2u(unsigned a, unsigned b, float c){
    return __builtin_amdgcn_fdot2(__builtin_bit_cast(h2f, a),
                                  __builtin_bit_cast(h2f, b), c, false);
}
__device__ __forceinline__ unsigned pk(float x, float y){
    return __builtin_bit_cast(unsigned, __builtin_amdgcn_cvt_pkrtz(x, y));
}

// ---- prep: slots bcast + row stats + f16 copies of k,v + weight transpose ----
__global__ __launch_bounds__(256) void k_prep(const float* __restrict__ mu,
        const float* __restrict__ kin, const float* __restrict__ vin,
        float* __restrict__ slots, __fp16* __restrict__ slotsh,
        float* __restrict__ kmu, float* __restrict__ krstd,
        float* __restrict__ vmu, float* __restrict__ vrstd,
        __fp16* __restrict__ kh, __fp16* __restrict__ vh,
        const float* __restrict__ Wq, const float* __restrict__ Wih,
        const float* __restrict__ Whh, const float* __restrict__ W1,
        const float* __restrict__ W2,
        uint2* __restrict__ TWq, uint2* __restrict__ TWih, uint2* __restrict__ TWhh,
        uint2* __restrict__ TW1, uint2* __restrict__ TW2){
    int bx = blockIdx.x, t = threadIdx.x;
    int gid = bx*256 + t;
    if (bx < 128){
        int idx = gid;                             // 32768 f4
        f4 v = ((const f4*)mu)[idx & 2047];
        ((f4*)slots)[idx] = v;
        uint2 o; o.x = pk(v.x, v.y); o.y = pk(v.z, v.w);
        ((uint2*)slotsh)[idx] = o;
    }
    int sub = t & 15;
    int rl  = t >> 4;
#pragma unroll
    for (int pass = 0; pass < 8; pass++){
        int task = bx*128 + pass*16 + rl;          // 0..131071
        int half = task >> 16;                     // 0: v, 1: k
        int row  = task & 65535;
        const float* src = half ? kin : vin;
        __fp16* dsth = half ? kh : vh;
        const f4* r4 = (const f4*)(src + (size_t)row*DD);
        uint2* w2 = (uint2*)(dsth + (size_t)row*DD);
        float s = 0.f, ss = 0.f;
#pragma unroll
        for (int k2 = 0; k2 < 8; k2++){
            f4 x = r4[sub + k2*16];
            s  += x.x+x.y+x.z+x.w;
            ss += x.x*x.x+x.y*x.y+x.z*x.z+x.w*x.w;
            uint2 o; o.x = pk(x.x, x.y); o.y = pk(x.z, x.w);
            w2[sub + k2*16] = o;
        }
        for (int o = 1; o < 16; o <<= 1){
            s += __shfl_xor(s, o); ss += __shfl_xor(ss, o);
        }
        if (sub == 0){
            float m = s*(1.f/DD);
            float rs = rsqrtf(ss*(1.f/DD) - m*m + LN_EPS_F);
            if (half){ kmu[row] = m; krstd[row] = rs; }
            else     { vmu[row] = m; vrstd[row] = rs; }
        }
    }
    // weight transpose-pack (f16)
    for (int id = gid; id < 589824; id += 262144){
        const float* W; uint2* TW; int R, local;
        if (id < 65536)      { W = Wq;  TW = TWq;  R = 512;  local = id; }
        else if (id < 262144){ W = Wih; TW = TWih; R = 1536; local = id - 65536; }
        else if (id < 458752){ W = Whh; TW = TWhh; R = 1536; local = id - 262144; }
        else if (id < 524288){ W = W1;  TW = TW1;  R = 512;  local = id - 458752; }
        else                 { W = W2;  TW = TW2;  R = 512;  local = id - 524288; }
        int kk = local / R, c = local - kk*R;
        f4 w = ((const f4*)W)[(size_t)c*128 + kk];
        uint2 o; o.x = pk(w.x, w.y); o.y = pk(w.z, w.w);
        TW[local] = o;
    }
}

// ---- fused LN(slots) + q-projection -> qgh (f16) ----
__global__ __launch_bounds__(256) void k_ln_q(const float* __restrict__ slots,
        const float* __restrict__ gs, const float* __restrict__ bs,
        const uint2* __restrict__ TWq, const float* __restrict__ bq,
        const float* __restrict__ gk, const float* __restrict__ bk,
        __fp16* __restrict__ qgh, float* __restrict__ C1p, float* __restrict__ C2p){
    __shared__ uint2 rowh[4][128];
    int lane = threadIdx.x & 63, wv = threadIdx.x >> 6;
    int m = blockIdx.y*4 + wv;
    int c = blockIdx.x*64 + lane;
    const f4* r4 = (const f4*)(slots + (size_t)m*DD);
    f4 v0 = r4[lane*2], v1 = r4[lane*2+1];
    float s  = v0.x+v0.y+v0.z+v0.w + v1.x+v1.y+v1.z+v1.w;
    float ss = v0.x*v0.x+v0.y*v0.y+v0.z*v0.z+v0.w*v0.w
             + v1.x*v1.x+v1.y*v1.y+v1.z*v1.z+v1.w*v1.w;
    for (int o = 32; o; o >>= 1){ s += __shfl_down(s,o); ss += __shfl_down(ss,o); }
    s = __shfl(s,0); ss = __shfl(ss,0);
    float mu = s*(1.f/DD);
    float rstd = rsqrtf(ss*(1.f/DD) - mu*mu + LN_EPS_F);
    const f4* g4 = (const f4*)gs; const f4* b4 = (const f4*)bs;
    f4 g0 = g4[lane*2], g1 = g4[lane*2+1], c0 = b4[lane*2], c1 = b4[lane*2+1];
    f4 o0, o1;
    o0.x=(v0.x-mu)*rstd*g0.x+c0.x; o0.y=(v0.y-mu)*rstd*g0.y+c0.y;
    o0.z=(v0.z-mu)*rstd*g0.z+c0.z; o0.w=(v0.w-mu)*rstd*g0.w+c0.w;
    o1.x=(v1.x-mu)*rstd*g1.x+c1.x; o1.y=(v1.y-mu)*rstd*g1.y+c1.y;
    o1.z=(v1.z-mu)*rstd*g1.z+c1.z; o1.w=(v1.w-mu)*rstd*g1.w+c1.w;
    rowh[wv][lane*2]     = uint2{pk(o0.x,o0.y), pk(o0.z,o0.w)};
    rowh[wv][lane*2 + 1] = uint2{pk(o1.x,o1.y), pk(o1.z,o1.w)};
    __syncthreads();
    float acc = 0.f;
    for (int kk = 0; kk < 128; kk++){
        uint2 q2 = rowh[wv][kk];
        uint2 w2 = TWq[(size_t)kk*512 + c];
        acc = fdot2u(w2.x, q2.x, acc);
        acc = fdot2u(w2.y, q2.y, acc);
    }
    float q0 = acc + bq[c];
    float qg0 = q0 * gk[c];
    float qg1 = __shfl_down(qg0, 1);
    if (!(lane & 1))
        ((unsigned*)qgh)[(size_t)m*256 + (c>>1)] = pk(qg0, qg1);
    float r1 = qg0, r2 = q0 * bk[c];
    for (int o = 32; o; o >>= 1){ r1 += __shfl_down(r1,o); r2 += __shfl_down(r2,o); }
    if (lane == 0){
        C1p[blockIdx.x*256 + m] = r1;
        C2p[blockIdx.x*256 + m] = r2;
    }
}

// ---- fused QK^T (MFMA) + inverted softmax + AV partial (paired fdot2) ----
// grid (64 chunks of 64 j, 16 b). Wave = 16 j-rows via one 16x16x32 MFMA chain.
__global__ __launch_bounds__(256, 4) void k_attn_av(const __fp16* __restrict__ kh,
        const __fp16* __restrict__ vh, const __fp16* __restrict__ qgh,
        const float* __restrict__ C1p, const float* __restrict__ C2p,
        const float* __restrict__ kmu, const float* __restrict__ krstd,
        const float* __restrict__ vmu, const float* __restrict__ vrstd,
        float* __restrict__ Sp, float* __restrict__ Mp, __fp16* __restrict__ Uwp,
        float* __restrict__ attn_out, int last){
    __shared__ __align__(16) unsigned qLr[16*260];   // q rows [slot][260 dw] 16.6 KB
    __shared__ __align__(16) unsigned wLp[32*20];    // w j-pairs [pair][16+pad]
    __shared__ float c1s[NSL], c2s[NSL];
    __shared__ float kmuL[64], krsL[64], vmuL[64], vrsL[64];
    __shared__ float spL[4][NSL], mpL[4][NSL];
    int chunk = blockIdx.x, b = blockIdx.y;
    int t = threadIdx.x, lane = t & 63, wv = t >> 6;

    const unsigned* qsrc = (const unsigned*)(qgh + (size_t)b*NSL*DD);
    for (int e = t; e < 4096; e += 256)
        qLr[(e >> 8)*260 + (e & 255)] = qsrc[e];
    if (t < NSL){
        float c1 = 0.f, c2 = 0.f;
#pragma unroll
        for (int k = 0; k < 8; k++){
            c1 += C1p[k*256 + b*NSL + t];
            c2 += C2p[k*256 + b*NSL + t];
        }
        c1s[t] = c1; c2s[t] = c2;
    }
    {
        int grp = t >> 6, j0 = t & 63;
        size_t gidx = (size_t)b*NN + chunk*64 + j0;
        if (grp == 0) kmuL[j0] = kmu[gidx];
        else if (grp == 1) krsL[j0] = krstd[gidx];
        else if (grp == 2) vmuL[j0] = vmu[gidx];
        else vrsL[j0] = vrstd[gidx];
    }
    __syncthreads();

    // ---- QK: MFMA 16x16x32, A = k rows, B = q^T ----
    int i = lane & 15, g = lane >> 4;
    int jbase = chunk*64 + wv*16;
    const uint4* ka = (const uint4*)(kh + ((size_t)b*NN + jbase + i)*DD);
    const uint4* qb4 = (const uint4*)qLr;
    f32x4 acc = {0.f, 0.f, 0.f, 0.f};
#pragma unroll
    for (int ks = 0; ks < 16; ks++){
        uint4 af = ka[ks*4 + g];
        uint4 bf = qb4[i*65 + ks*4 + g];
        acc = __builtin_amdgcn_mfma_f32_16x16x32_f16(
                  __builtin_bit_cast(h8, af), __builtin_bit_cast(h8, bf), acc, 0, 0, 0);
    }
    // lane holds dots[j = jbase + g*4 + r][slot i] in acc[r]
    float c1i = c1s[i], c2i = c2s[i];
    float a4[4], w4v[4];
    float S_part = 0.f, M_part = 0.f;
#pragma unroll
    for (int r = 0; r < 4; r++){
        int jl = g*4 + r;
        float mu = kmuL[wv*16 + jl], rstd = krsL[wv*16 + jl];
        float dv = SCALE_F*(rstd*(acc[r] - mu*c1i) + c2i);
        float mx = dv;
        mx = fmaxf(mx, __shfl_xor(mx, 1));
        mx = fmaxf(mx, __shfl_xor(mx, 2));
        mx = fmaxf(mx, __shfl_xor(mx, 4));
        mx = fmaxf(mx, __shfl_xor(mx, 8));
        float e = __expf(dv - mx);
        float se = e;
        se += __shfl_xor(se, 1);
        se += __shfl_xor(se, 2);
        se += __shfl_xor(se, 4);
        se += __shfl_xor(se, 8);
        float a = e/se + ATTN_EPS_F;
        a4[r] = a;
        float rv = vrsL[wv*16 + jl], vm = vmuL[wv*16 + jl];
        w4v[r] = a*rv;
        S_part += a;
        M_part += a*rv*vm;
    }
    wLp[(wv*8 + g*2)*20 + i]     = pk(w4v[0], w4v[1]);
    wLp[(wv*8 + g*2 + 1)*20 + i] = pk(w4v[2], w4v[3]);
    S_part += __shfl_xor(S_part, 16);
    S_part += __shfl_xor(S_part, 32);
    M_part += __shfl_xor(M_part, 16);
    M_part += __shfl_xor(M_part, 32);
    if (lane < 16){ spL[wv][lane] = S_part; mpL[wv][lane] = M_part; }
    if (last){
#pragma unroll
        for (int r = 0; r < 4; r++)
            attn_out[((size_t)b*NSL + i)*NN + jbase + g*4 + r] = a4[r];
    }
    __syncthreads();

    if (t < NSL)
        Sp[((size_t)b*NSL + t)*64 + chunk] = spL[0][t]+spL[1][t]+spL[2][t]+spL[3][t];
    else if (t < 2*NSL){
        int ii = t - NSL;
        Mp[((size_t)b*NSL + ii)*64 + chunk] = mpL[0][ii]+mpL[1][ii]+mpL[2][ii]+mpL[3][ii];
    }

    // ---- AV partial: paired-j fdot2 over the chunk's 64 j (32 pairs) ----
    f4 ax[4], ay[4];
#pragma unroll
    for (int g2 = 0; g2 < 4; g2++){ ax[g2] = f4{0,0,0,0}; ay[g2] = f4{0,0,0,0}; }
    const unsigned* v2h = (const unsigned*)(vh + ((size_t)b*NN + (size_t)chunk*64)*DD);
#pragma unroll 2
    for (int p = 0; p < 32; p++){
        unsigned vu0 = v2h[(size_t)(2*p)*256 + t];
        unsigned vu1 = v2h[(size_t)(2*p+1)*256 + t];
        unsigned pd0 = __builtin_amdgcn_perm(vu1, vu0, 0x05040100u);
        unsigned pd1 = __builtin_amdgcn_perm(vu1, vu0, 0x07060302u);
        const uint4* wp4 = (const uint4*)(wLp + p*20);
#pragma unroll
        for (int g2 = 0; g2 < 4; g2++){
            uint4 w = wp4[g2];
            ax[g2].x = fdot2u(w.x, pd0, ax[g2].x);
            ax[g2].y = fdot2u(w.y, pd0, ax[g2].y);
            ax[g2].z = fdot2u(w.z, pd0, ax[g2].z);
            ax[g2].w = fdot2u(w.w, pd0, ax[g2].w);
            ay[g2].x = fdot2u(w.x, pd1, ay[g2].x);
            ay[g2].y = fdot2u(w.y, pd1, ay[g2].y);
            ay[g2].z = fdot2u(w.z, pd1, ay[g2].z);
            ay[g2].w = fdot2u(w.w, pd1, ay[g2].w);
        }
    }
#pragma unroll
    for (int g2 = 0; g2 < 4; g2++){
        const float* px = (const float*)&ax[g2];
        const float* py = (const float*)&ay[g2];
#pragma unroll
        for (int c4 = 0; c4 < 4; c4++){
            int ii = g2*4 + c4;
            ((unsigned*)Uwp)[(((size_t)(b*NSL + ii))*64 + chunk)*256 + t] = pk(px[c4], py[c4]);
        }
    }
}

// ---- updates = gv*(sum Uwp - M)/S + bv -> updh (f16)  (block = row m) ----
__global__ __launch_bounds__(256) void k_upd(const __fp16* __restrict__ Uwp,
        const float* __restrict__ Sp, const float* __restrict__ Mp,
        const float* __restrict__ gv, const float* __restrict__ bv,
        __fp16* __restrict__ updh){
    __shared__ float sm[2];
    int m = blockIdx.x, t = threadIdx.x;
    if (t < 128){
        float val = (t < 64) ? Sp[(size_t)m*64 + (t&63)] : Mp[(size_t)m*64 + (t&63)];
        for (int o = 1; o < 64; o <<= 1) val += __shfl_xor(val, o);
        if (t == 0)  sm[0] = val;
        if (t == 64) sm[1] = val;
    }
    __syncthreads();
    float Sv = sm[0], Mv = sm[1];
    float rS = 1.f/Sv;
    float accx = 0.f, accy = 0.f;
    const unsigned* base = (const unsigned*)Uwp + (size_t)m*64*256 + t;
#pragma unroll 8
    for (int ch = 0; ch < 64; ch++){
        h2 u = __builtin_bit_cast(h2, base[(size_t)ch*256]);
        accx += (float)u.x; accy += (float)u.y;
    }
    float2 gvv = ((const float2*)gv)[t];
    float2 bvv = ((const float2*)bv)[t];
    float ox = gvv.x*(accx - Mv)*rS + bvv.x;
    float oy = gvv.y*(accy - Mv)*rS + bvv.y;
    ((unsigned*)updh)[(size_t)m*256 + t] = pk(ox, oy);
}

// ---- GRU gate matmuls, f16 + split-K x2: grid (32 cc, 16 mg, 2 ks) ----
__global__ __launch_bounds__(256) void k_gru_mm(const __fp16* __restrict__ xh, const __fp16* __restrict__ hh,
        const uint2* __restrict__ TWih, const float* __restrict__ bih,
        const uint2* __restrict__ TWhh, const float* __restrict__ bhh,
        float* __restrict__ gpA, float* __restrict__ gpB){
    int lane = threadIdx.x & 63, wv = threadIdx.x >> 6;
    int c = blockIdx.x*64 + lane;                 // 0..2047
    int m0 = blockIdx.y*16 + wv*4;
    int ks = blockIdx.z;
    int k0 = ks*64, k1 = k0 + 64;
    float* gp = ks ? gpB : gpA;
    int type = c >> 9;
    const uint2* x2 = (const uint2*)xh;
    const uint2* h2_ = (const uint2*)hh;
    float acc[4] = {0,0,0,0};
    float bias;
    if (type <= 1){
#pragma unroll 2
        for (int kk = k0; kk < k1; kk++){
            uint2 wa = TWih[(size_t)kk*1536 + c];
            uint2 wb = TWhh[(size_t)kk*1536 + c];
#pragma unroll
            for (int mm = 0; mm < 4; mm++){
                uint2 xa = x2[(size_t)(m0+mm)*128 + kk];
                uint2 ha = h2_[(size_t)(m0+mm)*128 + kk];
                acc[mm] = fdot2u(wa.x, xa.x, acc[mm]);
                acc[mm] = fdot2u(wa.y, xa.y, acc[mm]);
                acc[mm] = fdot2u(wb.x, ha.x, acc[mm]);
                acc[mm] = fdot2u(wb.y, ha.y, acc[mm]);
            }
        }
        bias = bih[c] + bhh[c];
    } else if (type == 2){
#pragma unroll 2
        for (int kk = k0; kk < k1; kk++){
            uint2 wa = TWih[(size_t)kk*1536 + c];
#pragma unroll
            for (int mm = 0; mm < 4; mm++){
                uint2 xa = x2[(size_t)(m0+mm)*128 + kk];
                acc[mm] = fdot2u(wa.x, xa.x, acc[mm]);
                acc[mm] = fdot2u(wa.y, xa.y, acc[mm]);
            }
        }
        bias = bih[c];
    } else {
        int cr = c - 512;
#pragma unroll 2
        for (int kk = k0; kk < k1; kk++){
            uint2 wb = TWhh[(size_t)kk*1536 + cr];
#pragma unroll
            for (int mm = 0; mm < 4; mm++){
                uint2 ha = h2_[(size_t)(m0+mm)*128 + kk];
                acc[mm] = fdot2u(wb.x, ha.x, acc[mm]);
                acc[mm] = fdot2u(wb.y, ha.y, acc[mm]);
            }
        }
        bias = bhh[cr];
    }
    float bout = ks ? 0.f : bias;
#pragma unroll
    for (int mm = 0; mm < 4; mm++)
        gp[(size_t)(m0+mm)*2048 + c] = acc[mm] + bout;
}

// ---- tail1: GRU-elem + LN(gff,bff) + FFN1 -> hidh; cc==0 writes slots2 ----
__global__ __launch_bounds__(256) void k_tail1(const float* __restrict__ gpA,
        const float* __restrict__ gpB, const float* __restrict__ slots,
        const float* __restrict__ gff, const float* __restrict__ bff,
        const uint2* __restrict__ TW1, const float* __restrict__ b1,
        float* __restrict__ slots2, __fp16* __restrict__ hidh){
    __shared__ uint2 rowh[4][128];
    int lane = threadIdx.x & 63, wv = threadIdx.x >> 6;
    int m = blockIdx.y*4 + wv;
    int c = blockIdx.x*64 + lane;
    const f4* g0 = (const f4*)(gpA + (size_t)m*2048);
    const f4* g1 = (const f4*)(gpB + (size_t)m*2048);
    const f4* h4 = (const f4*)(slots + (size_t)m*DD);
    f4 s2v[2];
    float s = 0.f, ss = 0.f;
#pragma unroll
    for (int half = 0; half < 2; half++){
        int e = lane*2 + half;
        f4 rp = g0[e],      zp = g0[128+e],  nx = g0[256+e],  nh = g0[384+e];
        f4 rq = g1[e],      zq = g1[128+e],  ny = g1[256+e],  nz = g1[384+e];
        rp.x+=rq.x; rp.y+=rq.y; rp.z+=rq.z; rp.w+=rq.w;
        zp.x+=zq.x; zp.y+=zq.y; zp.z+=zq.z; zp.w+=zq.w;
        nx.x+=ny.x; nx.y+=ny.y; nx.z+=ny.z; nx.w+=ny.w;
        nh.x+=nz.x; nh.y+=nz.y; nh.z+=nz.z; nh.w+=nz.w;
        f4 hv = h4[e];
        f4 o;
        {
            float r = 1.f/(1.f + __expf(-rp.x));
            float z = 1.f/(1.f + __expf(-zp.x));
            float n = tanhf(nx.x + r*nh.x);
            o.x = (1.f - z)*n + z*hv.x;
            r = 1.f/(1.f + __expf(-rp.y)); z = 1.f/(1.f + __expf(-zp.y));
            n = tanhf(nx.y + r*nh.y);
            o.y = (1.f - z)*n + z*hv.y;
            r = 1.f/(1.f + __expf(-rp.z)); z = 1.f/(1.f + __expf(-zp.z));
            n = tanhf(nx.z + r*nh.z);
            o.z = (1.f - z)*n + z*hv.z;
            r = 1.f/(1.f + __expf(-rp.w)); z = 1.f/(1.f + __expf(-zp.w));
            n = tanhf(nx.w + r*nh.w);
            o.w = (1.f - z)*n + z*hv.w;
        }
        s2v[half] = o;
        s  += o.x+o.y+o.z+o.w;
        ss += o.x*o.x+o.y*o.y+o.z*o.z+o.w*o.w;
        if (blockIdx.x == 0)
            ((f4*)(slots2 + (size_t)m*DD))[e] = o;
    }
    for (int o = 32; o; o >>= 1){ s += __shfl_down(s,o); ss += __shfl_down(ss,o); }
    s = __shfl(s,0); ss = __shfl(ss,0);
    float mu = s*(1.f/DD);
    float rstd = rsqrtf(ss*(1.f/DD) - mu*mu + LN_EPS_F);
    const f4* gg4 = (const f4*)gff; const f4* bb4 = (const f4*)bff;
#pragma unroll
    for (int half = 0; half < 2; half++){
        int e = lane*2 + half;
        f4 gg = gg4[e], bb = bb4[e], o = s2v[half], n;
        n.x = (o.x-mu)*rstd*gg.x + bb.x;
        n.y = (o.y-mu)*rstd*gg.y + bb.y;
        n.z = (o.z-mu)*rstd*gg.z + bb.z;
        n.w = (o.w-mu)*rstd*gg.w + bb.w;
        rowh[wv][e] = uint2{pk(n.x,n.y), pk(n.z,n.w)};
    }
    __syncthreads();
    float acc = 0.f;
    for (int kk = 0; kk < 128; kk++){
        uint2 q2 = rowh[wv][kk];
        uint2 w2 = TW1[(size_t)kk*512 + c];
        acc = fdot2u(w2.x, q2.x, acc);
        acc = fdot2u(w2.y, q2.y, acc);
    }
    float hv = fmaxf(acc + b1[c], 0.f);
    hidh[(size_t)m*DD + c] = (__fp16)hv;
}

// ---- FFN2: f16 hid/W2 + slots2 residual -> slots f32 + slotsh f16 (+out) ----
__global__ __launch_bounds__(256) void k_ffn2(const __fp16* __restrict__ hidh, const uint2* __restrict__ TW2,
                                              const float* __restrict__ b2, const float* __restrict__ slots2,
                                              float* __restrict__ slots, __fp16* __restrict__ slotsh,
                                              float* __restrict__ out_slots, int last){
    int lane = threadIdx.x & 63, wv = threadIdx.x >> 6;
    int d = blockIdx.x*64 + lane;
    int m = blockIdx.y*4 + wv;
    const uint2* h2_ = (const uint2*)(hidh + (size_t)m*DD);
    float acc = 0.f;
    for (int kk = 0; kk < 128; kk++){
        uint2 hh = h2_[kk];
        uint2 w2 = TW2[(size_t)kk*512 + d];
        acc = fdot2u(w2.x, hh.x, acc);
        acc = fdot2u(w2.y, hh.y, acc);
    }
    float v0 = slots2[(size_t)m*DD + d] + acc + b2[d];
    slots[(size_t)m*DD + d] = v0;
    slotsh[(size_t)m*DD + d] = (__fp16)v0;
    if (last) out_slots[(size_t)m*DD + d] = v0;
}

// ---- features ----
__global__ __launch_bounds__(256) void k_features(const float* __restrict__ prompts, const float* __restrict__ slots,
        const float* __restrict__ attn, float* __restrict__ pf, float* __restrict__ sf, float* __restrict__ sf2){
    int b = blockIdx.y;
    int pbase = blockIdx.x*32;
    int t = threadIdx.x;
    __shared__ float al[NSL][33];
    for (int idx = t; idx < NSL*32; idx += 256){
        int i = idx >> 5, pp = idx & 31;
        al[i][pp] = attn[((size_t)b*NSL + i)*NN + pbase + pp];
    }
    float2 pr[NSL], sl[NSL];
    const float2* p2 = (const float2*)prompts;
    const float2* s2 = (const float2*)(slots + (size_t)b*NSL*DD);
#pragma unroll
    for (int i = 0; i < NSL; i++){ pr[i] = p2[i*256+t]; sl[i] = s2[i*256+t]; }
    __syncthreads();
    for (int pp = 0; pp < 32; pp++){
        float a0=0.f, a1=0.f, c0=0.f, c1=0.f;
#pragma unroll
        for (int i = 0; i < NSL; i++){
            float a = al[i][pp];
            a0 += a*pr[i].x; a1 += a*pr[i].y;
            c0 += a*sl[i].x; c1 += a*sl[i].y;
        }
        size_t o = ((size_t)b*NN + pbase + pp)*DD + 2*t;
        float2 pv; pv.x=a0; pv.y=a1;
        float2 sv; sv.x=c0; sv.y=c1;
        *(float2*)(pf + o)  = pv;
        *(float2*)(sf + o)  = sv;
        *(float2*)(sf2 + o) = sv;
    }
}

extern "C" void kernel_launch(void* const* d_in, const int* in_sizes, int n_in,
                              void* d_out, int out_size, void* d_ws, size_t ws_size,
                              hipStream_t stream) {
    const float* k_inp   = (const float*)d_in[2];
    const float* v_inp   = (const float*)d_in[3];
    const float* slots_mu= (const float*)d_in[4];
    const float* prompts = (const float*)d_in[5];
    const float* Wq      = (const float*)d_in[6];
    const float* bq      = (const float*)d_in[7];
    const float* W_ih    = (const float*)d_in[8];
    const float* b_ih    = (const float*)d_in[9];
    const float* W_hh    = (const float*)d_in[10];
    const float* b_hh    = (const float*)d_in[11];
    const float* W1      = (const float*)d_in[12];
    const float* b1      = (const float*)d_in[13];
    const float* W2      = (const float*)d_in[14];
    const float* b2      = (const float*)d_in[15];
    const float* gk      = (const float*)d_in[16];
    const float* bk      = (const float*)d_in[17];
    const float* gv      = (const float*)d_in[18];
    const float* bv      = (const float*)d_in[19];
    const float* gs      = (const float*)d_in[20];
    const float* bs      = (const float*)d_in[21];
    const float* gff     = (const float*)d_in[22];
    const float* bff     = (const float*)d_in[23];

    float* ws = (float*)d_ws;
    float* slots   = ws + 0;           // 131072
    float* slots2  = ws + 131072;      // 131072
    float* gp      = ws + 262144;      // 524288 -> 786432
    float* C1p     = ws + 786432;      // 2048
    float* C2p     = ws + 788480;      // 2048
    float* kmu     = ws + 790528;      // 65536
    float* krstd   = ws + 856064;      // 65536
    float* vmu     = ws + 921600;      // 65536
    float* vrstd   = ws + 987136;      // 65536
    float* Sp      = ws + 1052672;     // 16384
    float* Mp      = ws + 1069056;     // 16384 -> 1085440
    __fp16* slotsh = (__fp16*)(ws + 1085440);   // 65536 float-slots
    __fp16* updh   = (__fp16*)(ws + 1150976);   // 65536
    __fp16* hidh   = (__fp16*)(ws + 1216512);   // 65536
    __fp16* qgh    = (__fp16*)(ws + 1282048);   // 65536 -> 1347584
    uint2* TWqh  = (uint2*)(ws + 1347584);      // 131072 -> 1478656
    uint2* TWihh = (uint2*)(ws + 1478656);      // 393216 -> 1871872
    uint2* TWhhh = (uint2*)(ws + 1871872);      // 393216 -> 2265088
    uint2* TW1h  = (uint2*)(ws + 2265088);      // 131072 -> 2396160
    uint2* TW2h  = (uint2*)(ws + 2396160);      // 131072 -> 2527232 floats = 10.1 MB

    float* out      = (float*)d_out;
    float* attn_out = out + 131072;
    float* pf       = out + 1179648;
    float* sf       = pf + 33554432;
    float* sf2      = sf + 33554432;
    __fp16* Uwp     = (__fp16*)pf;           // 8.4M f16 scratch in pf region
    float* gpB      = pf + 16777216;         // 0.5M floats scratch in pf region
    __fp16* kh      = (__fp16*)sf;           // 67 MB f16 k in sf region
    __fp16* vh      = (__fp16*)sf2;          // 67 MB f16 v in sf2 region
    // pf/sf/sf2 scratch fully consumed before k_features overwrites those regions

    k_prep<<<1024, 256, 0, stream>>>(slots_mu, k_inp, v_inp, slots, slotsh,
                                     kmu, krstd, vmu, vrstd, kh, vh,
                                     Wq, W_ih, W_hh, W1, W2,
                                     TWqh, TWihh, TWhhh, TW1h, TW2h);

    for (int it = 0; it < 3; it++){
        int last = (it == 2);
        k_ln_q<<<dim3(8,64), 256, 0, stream>>>(slots, gs, bs, TWqh, bq, gk, bk, qgh, C1p, C2p);
        k_attn_av<<<dim3(64,16), 256, 0, stream>>>(kh, vh, qgh, C1p, C2p,
                                                   kmu, krstd, vmu, vrstd,
                                                   Sp, Mp, Uwp, attn_out, last);
        k_upd<<<256, 256, 0, stream>>>(Uwp, Sp, Mp, gv, bv, updh);
        k_gru_mm<<<dim3(32,16,2), 256, 0, stream>>>(updh, slotsh, TWihh, b_ih, TWhhh, b_hh, gp, gpB);
        k_tail1<<<dim3(8,64), 256, 0, stream>>>(gp, gpB, slots, gff, bff, TW1h, b1, slots2, hidh);
        k_ffn2<<<dim3(8,64), 256, 0, stream>>>(hidh, TW2h, b2, slots2, slots, slotsh, out, last);
    }

    k_features<<<dim3(128,16), 256, 0, stream>>>(prompts, slots, attn_out, pf, sf, sf2);
}